// Round 1
// baseline (223.370 us; speedup 1.0000x reference)
//
#include <hip/hip_runtime.h>

using f32x4 = __attribute__((ext_vector_type(4))) float;
using s8v   = __attribute__((ext_vector_type(8))) short;
using us4v  = __attribute__((ext_vector_type(4))) unsigned short;

__device__ inline unsigned short f2bf(float f) {
    union { float fl; unsigned int u; } v; v.fl = f;
    unsigned int u = v.u;
    return (unsigned short)((u + 0x7fffu + ((u >> 16) & 1u)) >> 16);
}
__device__ inline float bf2f(unsigned short h) {
    union { unsigned int u; float fl; } v; v.u = ((unsigned int)h) << 16;
    return v.fl;
}

#define MFMA16(a, b, c) __builtin_amdgcn_mfma_f32_16x16x32_bf16((a), (b), (c), 0, 0, 0)

// ---------------------------------------------------------------------------
// Stage 1: qkv = x @ w_qkv^T   (A fp32 [4608,768], B fp32 [2304,768])
// Split bf16 hi/lo, 3-term MFMA for ~fp32 accuracy. C written as bf16.
// ---------------------------------------------------------------------------
__global__ __launch_bounds__(256) void gemm_qkv(const float* __restrict__ A,
                                                const float* __restrict__ B,
                                                unsigned short* __restrict__ C) {
    constexpr int K = 768, LDA = 768, LDB = 768, LDC = 2304;
    __shared__ unsigned short sAh[128][40], sAl[128][40], sBh[128][40], sBl[128][40];
    const int tid = threadIdx.x, lane = tid & 63, wv = tid >> 6;
    const int wm = (wv >> 1) * 64, wn = (wv & 1) * 64;
    const int m0 = blockIdx.y * 128, n0 = blockIdx.x * 128;
    const int fr = lane & 15, fk = (lane >> 4) * 8;

    f32x4 acc[4][4];
#pragma unroll
    for (int m = 0; m < 4; ++m)
#pragma unroll
        for (int n2 = 0; n2 < 4; ++n2) acc[m][n2] = (f32x4){0.f, 0.f, 0.f, 0.f};

    for (int kt = 0; kt < K / 32; ++kt) {
        const int k0 = kt * 32;
#pragma unroll
        for (int i = 0; i < 4; ++i) {
            const int el = i * 1024 + tid * 4;
            const int r = el >> 5, c = el & 31;
            float4 av = *(const float4*)(A + (size_t)(m0 + r) * LDA + k0 + c);
            float4 bv = *(const float4*)(B + (size_t)(n0 + r) * LDB + k0 + c);
            us4v ahv, alv, bhv, blv;
            unsigned short h;
            h = f2bf(av.x); ahv[0] = h; alv[0] = f2bf(av.x - bf2f(h));
            h = f2bf(av.y); ahv[1] = h; alv[1] = f2bf(av.y - bf2f(h));
            h = f2bf(av.z); ahv[2] = h; alv[2] = f2bf(av.z - bf2f(h));
            h = f2bf(av.w); ahv[3] = h; alv[3] = f2bf(av.w - bf2f(h));
            h = f2bf(bv.x); bhv[0] = h; blv[0] = f2bf(bv.x - bf2f(h));
            h = f2bf(bv.y); bhv[1] = h; blv[1] = f2bf(bv.y - bf2f(h));
            h = f2bf(bv.z); bhv[2] = h; blv[2] = f2bf(bv.z - bf2f(h));
            h = f2bf(bv.w); bhv[3] = h; blv[3] = f2bf(bv.w - bf2f(h));
            *(us4v*)&sAh[r][c] = ahv; *(us4v*)&sAl[r][c] = alv;
            *(us4v*)&sBh[r][c] = bhv; *(us4v*)&sBl[r][c] = blv;
        }
        __syncthreads();

        s8v fah[4], fal[4], fbh[4], fbl[4];
#pragma unroll
        for (int m = 0; m < 4; ++m) {
            fah[m] = *(const s8v*)&sAh[wm + m * 16 + fr][fk];
            fal[m] = *(const s8v*)&sAl[wm + m * 16 + fr][fk];
        }
#pragma unroll
        for (int n2 = 0; n2 < 4; ++n2) {
            fbh[n2] = *(const s8v*)&sBh[wn + n2 * 16 + fr][fk];
            fbl[n2] = *(const s8v*)&sBl[wn + n2 * 16 + fr][fk];
        }
#pragma unroll
        for (int m = 0; m < 4; ++m)
#pragma unroll
            for (int n2 = 0; n2 < 4; ++n2) {
                acc[m][n2] = MFMA16(fah[m], fbh[n2], acc[m][n2]);
                acc[m][n2] = MFMA16(fah[m], fbl[n2], acc[m][n2]);
                acc[m][n2] = MFMA16(fal[m], fbh[n2], acc[m][n2]);
            }
        __syncthreads();
    }

    const int rg = (lane >> 4) * 4;
#pragma unroll
    for (int m = 0; m < 4; ++m)
#pragma unroll
        for (int n2 = 0; n2 < 4; ++n2)
#pragma unroll
            for (int r = 0; r < 4; ++r)
                C[(size_t)(m0 + wm + m * 16 + rg + r) * LDC + (n0 + wn + n2 * 16 + fr)] =
                    f2bf(acc[m][n2][r]);
}

// ---------------------------------------------------------------------------
// Stage 1.5: Vt[n][head][e][token] = V[n][token][head][e]  (bf16)
// ---------------------------------------------------------------------------
__global__ __launch_bounds__(256) void vtrans(const unsigned short* __restrict__ qkv,
                                              unsigned short* __restrict__ vt) {
    __shared__ unsigned short t[64][72];
    const int tt = blockIdx.x, head = blockIdx.y, n = blockIdx.z;
    const int tid = threadIdx.x;
#pragma unroll
    for (int i = 0; i < 2; ++i) {
        const int el = i * 2048 + tid * 8;
        const int tr = el >> 6, c = el & 63;
        s8v v = *(const s8v*)(qkv + (size_t)(n * 2304 + tt * 64 + tr) * 2304 + 1536 + head * 64 + c);
        *(s8v*)&t[tr][c] = v;
    }
    __syncthreads();
#pragma unroll
    for (int i = 0; i < 2; ++i) {
        const int el = i * 2048 + tid * 8;
        const int er = el >> 6, tk = el & 63;
        s8v w;
#pragma unroll
        for (int j = 0; j < 8; ++j) w[j] = (short)t[tk + j][er];
        *(s8v*)(vt + (size_t)((n * 12 + head) * 64 + er) * 2304 + tt * 64 + tk) = w;
    }
}

// ---------------------------------------------------------------------------
// Stage 2: neighborhood attention. Block = (qx, head, n), 3 waves x 16 queries.
// ---------------------------------------------------------------------------
__global__ __launch_bounds__(192) void attn_kernel(const unsigned short* __restrict__ qkv,
                                                   const unsigned short* __restrict__ vt,
                                                   unsigned short* __restrict__ o,
                                                   const int* __restrict__ ksp) {
    __shared__ unsigned short pbuf[3][16][72];
    const int lane = threadIdx.x & 63, wv = threadIdx.x >> 6;
    const int qx = blockIdx.x, head = blockIdx.y, n = blockIdx.z;
    const int fr = lane & 15, fg = lane >> 4;
    const int KS = *ksp;

    // zero P pad columns 48..63 (never rewritten)
#pragma unroll
    for (int i = 0; i < 4; ++i) pbuf[wv][fr][48 + fg * 4 + i] = 0;

    const int qtok = qx * 48 + wv * 16 + fr;
    const unsigned short* qrow = qkv + (size_t)(n * 2304 + qtok) * 2304 + head * 64;
    const s8v qa0 = *(const s8v*)(qrow + fg * 8);
    const s8v qa1 = *(const s8v*)(qrow + 32 + fg * 8);

    f32x4 Oacc[4];
#pragma unroll
    for (int e = 0; e < 4; ++e) Oacc[e] = (f32x4){0.f, 0.f, 0.f, 0.f};
    float mrow[4] = {-1e30f, -1e30f, -1e30f, -1e30f};
    float lrow[4] = {0.f, 0.f, 0.f, 0.f};

    const int kx0 = (qx - KS) > 0 ? (qx - KS) : 0;
    const int kx1 = (qx + KS) < 47 ? (qx + KS) : 47;

    for (int kx = kx0; kx <= kx1; ++kx) {
        // --- QK^T (3 n-tiles of 16 keys) ---
        f32x4 s[3];
#pragma unroll
        for (int nt = 0; nt < 3; ++nt) {
            const int ktok = kx * 48 + nt * 16 + fr;
            const unsigned short* krow = qkv + (size_t)(n * 2304 + ktok) * 2304 + 768 + head * 64;
            s8v kb0 = *(const s8v*)(krow + fg * 8);
            s8v kb1 = *(const s8v*)(krow + 32 + fg * 8);
            f32x4 z = (f32x4){0.f, 0.f, 0.f, 0.f};
            z = MFMA16(qa0, kb0, z);
            z = MFMA16(qa1, kb1, z);
            s[nt] = z;
        }
        // --- scale + mask + row max ---
        float vmax[4] = {-1e30f, -1e30f, -1e30f, -1e30f};
#pragma unroll
        for (int nt = 0; nt < 3; ++nt) {
            const int ky = nt * 16 + fr;
#pragma unroll
            for (int r = 0; r < 4; ++r) {
                const int qy = wv * 16 + fg * 4 + r;
                float v = s[nt][r] * 0.125f;
                const int dy = ky - qy;
                if (dy < -KS || dy > KS) v = -1e30f;
                s[nt][r] = v;
                vmax[r] = fmaxf(vmax[r], v);
            }
        }
#pragma unroll
        for (int d = 1; d < 16; d <<= 1)
#pragma unroll
            for (int r = 0; r < 4; ++r) vmax[r] = fmaxf(vmax[r], __shfl_xor(vmax[r], d));

        // --- online softmax update ---
        float sf[4], rs[4];
#pragma unroll
        for (int r = 0; r < 4; ++r) {
            const float mn = fmaxf(mrow[r], vmax[r]);
            sf[r] = __expf(mrow[r] - mn);
            mrow[r] = mn;
        }
#pragma unroll
        for (int nt = 0; nt < 3; ++nt)
#pragma unroll
            for (int r = 0; r < 4; ++r) s[nt][r] = __expf(s[nt][r] - mrow[r]);
#pragma unroll
        for (int r = 0; r < 4; ++r) rs[r] = s[0][r] + s[1][r] + s[2][r];
#pragma unroll
        for (int d = 1; d < 16; d <<= 1)
#pragma unroll
            for (int r = 0; r < 4; ++r) rs[r] += __shfl_xor(rs[r], d);
#pragma unroll
        for (int r = 0; r < 4; ++r) lrow[r] = lrow[r] * sf[r] + rs[r];
#pragma unroll
        for (int e = 0; e < 4; ++e)
#pragma unroll
            for (int r = 0; r < 4; ++r) Oacc[e][r] *= sf[r];

        // --- P -> LDS (A-fragment layout source) ---
#pragma unroll
        for (int nt = 0; nt < 3; ++nt)
#pragma unroll
            for (int r = 0; r < 4; ++r)
                pbuf[wv][fg * 4 + r][nt * 16 + fr] = f2bf(s[nt][r]);
        __syncthreads();

        const s8v pa0 = *(const s8v*)&pbuf[wv][fr][fg * 8];
        const s8v pa1 = *(const s8v*)&pbuf[wv][fr][32 + fg * 8];

        // --- PV ---
        const unsigned short* vbase = vt + (size_t)((n * 12 + head) * 64) * 2304 + kx * 48;
#pragma unroll
        for (int et = 0; et < 4; ++et) {
            const unsigned short* vrow = vbase + (size_t)(et * 16 + fr) * 2304;
            s8v vb0 = *(const s8v*)(vrow + fg * 8);
            s8v vb1 = *(const s8v*)(vrow + 32 + fg * 8);
            Oacc[et] = MFMA16(pa0, vb0, Oacc[et]);
            Oacc[et] = MFMA16(pa1, vb1, Oacc[et]);
        }
        __syncthreads();
    }

    // --- epilogue: divide by l, write o[n][token][head*64+e] as bf16 ---
    unsigned short* obase = o + (size_t)(n * 2304 + qx * 48 + wv * 16) * 768 + head * 64;
#pragma unroll
    for (int r = 0; r < 4; ++r) {
        const float inv = 1.f / lrow[r];
#pragma unroll
        for (int et = 0; et < 4; ++et)
            obase[(size_t)(fg * 4 + r) * 768 + et * 16 + fr] = f2bf(Oacc[et][r] * inv);
    }
}

// ---------------------------------------------------------------------------
// Stage 3: out = o @ w_out^T   (A bf16 [4608,768], B fp32 [768,768], C fp32)
// ---------------------------------------------------------------------------
__global__ __launch_bounds__(256) void gemm_out(const unsigned short* __restrict__ A,
                                                const float* __restrict__ B,
                                                float* __restrict__ C) {
    constexpr int K = 768, LDA = 768, LDB = 768, LDC = 768;
    __shared__ unsigned short sA[128][40], sB[128][40];
    const int tid = threadIdx.x, lane = tid & 63, wv = tid >> 6;
    const int wm = (wv >> 1) * 64, wn = (wv & 1) * 64;
    const int m0 = blockIdx.y * 128, n0 = blockIdx.x * 128;
    const int fr = lane & 15, fk = (lane >> 4) * 8;

    f32x4 acc[4][4];
#pragma unroll
    for (int m = 0; m < 4; ++m)
#pragma unroll
        for (int n2 = 0; n2 < 4; ++n2) acc[m][n2] = (f32x4){0.f, 0.f, 0.f, 0.f};

    for (int kt = 0; kt < K / 32; ++kt) {
        const int k0 = kt * 32;
#pragma unroll
        for (int i = 0; i < 2; ++i) {
            const int el = i * 2048 + tid * 8;
            const int r = el >> 5, c = el & 31;
            *(s8v*)&sA[r][c] = *(const s8v*)(A + (size_t)(m0 + r) * LDA + k0 + c);
        }
#pragma unroll
        for (int i = 0; i < 4; ++i) {
            const int el = i * 1024 + tid * 4;
            const int r = el >> 5, c = el & 31;
            float4 bv = *(const float4*)(B + (size_t)(n0 + r) * LDB + k0 + c);
            us4v bhv;
            bhv[0] = f2bf(bv.x); bhv[1] = f2bf(bv.y);
            bhv[2] = f2bf(bv.z); bhv[3] = f2bf(bv.w);
            *(us4v*)&sB[r][c] = bhv;
        }
        __syncthreads();

        s8v fa[4], fb[4];
#pragma unroll
        for (int m = 0; m < 4; ++m) fa[m] = *(const s8v*)&sA[wm + m * 16 + fr][fk];
#pragma unroll
        for (int n2 = 0; n2 < 4; ++n2) fb[n2] = *(const s8v*)&sB[wn + n2 * 16 + fr][fk];
#pragma unroll
        for (int m = 0; m < 4; ++m)
#pragma unroll
            for (int n2 = 0; n2 < 4; ++n2) acc[m][n2] = MFMA16(fa[m], fb[n2], acc[m][n2]);
        __syncthreads();
    }

    const int rg = (lane >> 4) * 4;
#pragma unroll
    for (int m = 0; m < 4; ++m)
#pragma unroll
        for (int n2 = 0; n2 < 4; ++n2)
#pragma unroll
            for (int r = 0; r < 4; ++r)
                C[(size_t)(m0 + wm + m * 16 + rg + r) * LDC + (n0 + wn + n2 * 16 + fr)] =
                    acc[m][n2][r];
}

// ---------------------------------------------------------------------------
extern "C" void kernel_launch(void* const* d_in, const int* in_sizes, int n_in,
                              void* d_out, int out_size, void* d_ws, size_t ws_size,
                              hipStream_t stream) {
    const float* x     = (const float*)d_in[0];
    const float* w_qkv = (const float*)d_in[1];
    const float* w_out = (const float*)d_in[2];
    const int*   ksp   = (const int*)d_in[3];
    float* out = (float*)d_out;

    char* ws = (char*)d_ws;
    unsigned short* qkv = (unsigned short*)ws;                         // 4608*2304 bf16 = 21,233,664 B
    unsigned short* vt  = (unsigned short*)(ws + 21233664);            // 2*12*64*2304 + slack = 7,078,016 B
    unsigned short* o   = (unsigned short*)(ws + 21233664 + 7078016);  // 4608*768 bf16 = 7,077,888 B

    gemm_qkv<<<dim3(18, 36), 256, 0, stream>>>(x, w_qkv, qkv);
    vtrans<<<dim3(36, 12, 2), 256, 0, stream>>>(qkv, vt);
    attn_kernel<<<dim3(48, 12, 2), 192, 0, stream>>>(qkv, vt, o, ksp);
    gemm_out<<<dim3(6, 36), 256, 0, stream>>>(o, w_out, out);
}

// Round 2
// 191.406 us; speedup vs baseline: 1.1670x; 1.1670x over previous
//
#include <hip/hip_runtime.h>

using f32x4 = __attribute__((ext_vector_type(4))) float;
using s8v   = __attribute__((ext_vector_type(8))) short;
using us4v  = __attribute__((ext_vector_type(4))) unsigned short;

__device__ inline unsigned short f2bf(float f) {
    union { float fl; unsigned int u; } v; v.fl = f;
    unsigned int u = v.u;
    return (unsigned short)((u + 0x7fffu + ((u >> 16) & 1u)) >> 16);
}
__device__ inline float bf2f(unsigned short h) {
    union { unsigned int u; float fl; } v; v.u = ((unsigned int)h) << 16;
    return v.fl;
}

#define MFMA16(a, b, c) __builtin_amdgcn_mfma_f32_16x16x32_bf16((a), (b), (c), 0, 0, 0)

typedef __attribute__((address_space(3))) unsigned int lds_uint;
typedef const __attribute__((address_space(1))) unsigned int glb_uint;
__device__ inline void gload16(void* l, const void* g) {
    __builtin_amdgcn_global_load_lds((glb_uint*)g, (lds_uint*)l, 16, 0, 0);
}

// ---------------------------------------------------------------------------
// Split fp32 -> bf16 hi + bf16 lo (residual). 8 elements / thread.
// ---------------------------------------------------------------------------
__global__ __launch_bounds__(256) void split_hl(const float* __restrict__ in,
                                                unsigned short* __restrict__ hi,
                                                unsigned short* __restrict__ lo,
                                                int n8) {
    const int i = blockIdx.x * blockDim.x + threadIdx.x;
    if (i >= n8) return;
    const float4 a = *(const float4*)(in + (size_t)i * 8);
    const float4 b = *(const float4*)(in + (size_t)i * 8 + 4);
    s8v h, l;
    unsigned short t;
    t = f2bf(a.x); h[0] = t; l[0] = f2bf(a.x - bf2f(t));
    t = f2bf(a.y); h[1] = t; l[1] = f2bf(a.y - bf2f(t));
    t = f2bf(a.z); h[2] = t; l[2] = f2bf(a.z - bf2f(t));
    t = f2bf(a.w); h[3] = t; l[3] = f2bf(a.w - bf2f(t));
    t = f2bf(b.x); h[4] = t; l[4] = f2bf(b.x - bf2f(t));
    t = f2bf(b.y); h[5] = t; l[5] = f2bf(b.y - bf2f(t));
    t = f2bf(b.z); h[6] = t; l[6] = f2bf(b.z - bf2f(t));
    t = f2bf(b.w); h[7] = t; l[7] = f2bf(b.w - bf2f(t));
    *(s8v*)(hi + (size_t)i * 8) = h;
    *(s8v*)(lo + (size_t)i * 8) = l;
}

// fp32 -> bf16 (hi only), for w_out
__global__ __launch_bounds__(256) void conv_bf16(const float* __restrict__ in,
                                                 unsigned short* __restrict__ hi, int n8) {
    const int i = blockIdx.x * blockDim.x + threadIdx.x;
    if (i >= n8) return;
    const float4 a = *(const float4*)(in + (size_t)i * 8);
    const float4 b = *(const float4*)(in + (size_t)i * 8 + 4);
    s8v h;
    h[0] = f2bf(a.x); h[1] = f2bf(a.y); h[2] = f2bf(a.z); h[3] = f2bf(a.w);
    h[4] = f2bf(b.x); h[5] = f2bf(b.y); h[6] = f2bf(b.z); h[7] = f2bf(b.w);
    *(s8v*)(hi + (size_t)i * 8) = h;
}

// ---------------------------------------------------------------------------
// Stage 1: qkv = x @ w_qkv^T, 3-term split bf16 MFMA (m97 structure).
// A-side: Ah/Al [4608,768] bf16.  B-side: Bh/Bl [2304,768] bf16.  C bf16.
// ---------------------------------------------------------------------------
__global__ __launch_bounds__(256) void gemm_qkv2(const unsigned short* __restrict__ Ah,
                                                 const unsigned short* __restrict__ Al,
                                                 const unsigned short* __restrict__ Bh,
                                                 const unsigned short* __restrict__ Bl,
                                                 unsigned short* __restrict__ C) {
    constexpr int LD = 768, LDC = 2304;
    __shared__ __align__(16) unsigned short sAh[128][32], sAl[128][32];
    __shared__ __align__(16) unsigned short sBh[128][32], sBl[128][32];
    const int tid = threadIdx.x, lane = tid & 63, wv = tid >> 6;
    const int wm = (wv >> 1) * 64, wn = (wv & 1) * 64;
    const int m0 = blockIdx.y * 128, n0 = blockIdx.x * 128;
    const int fr = lane & 15, fkb = (lane >> 4) * 8;

    // staging: thread t covers rows t/4 and 64+t/4, 8 elems at col (t&3)*8
    const int srow = tid >> 2, scol = (tid & 3) * 8;
    const unsigned short* gAh = Ah + (size_t)(m0 + srow) * LD + scol;
    const unsigned short* gAl = Al + (size_t)(m0 + srow) * LD + scol;
    const unsigned short* gBh = Bh + (size_t)(n0 + srow) * LD + scol;
    const unsigned short* gBl = Bl + (size_t)(n0 + srow) * LD + scol;

    f32x4 acc[4][4];
#pragma unroll
    for (int m = 0; m < 4; ++m)
#pragma unroll
        for (int n2 = 0; n2 < 4; ++n2) acc[m][n2] = (f32x4){0.f, 0.f, 0.f, 0.f};

    for (int kt = 0; kt < 24; ++kt) {
        const int k0 = kt * 32;
        gload16(&sAh[srow][scol],      gAh + k0);
        gload16(&sAh[64 + srow][scol], gAh + 64 * LD + k0);
        gload16(&sAl[srow][scol],      gAl + k0);
        gload16(&sAl[64 + srow][scol], gAl + 64 * LD + k0);
        gload16(&sBh[srow][scol],      gBh + k0);
        gload16(&sBh[64 + srow][scol], gBh + 64 * LD + k0);
        gload16(&sBl[srow][scol],      gBl + k0);
        gload16(&sBl[64 + srow][scol], gBl + 64 * LD + k0);
        __syncthreads();

        s8v fah[4], fal[4], fbh[4], fbl[4];
#pragma unroll
        for (int m = 0; m < 4; ++m) {
            fah[m] = *(const s8v*)&sAh[wm + m * 16 + fr][fkb];
            fal[m] = *(const s8v*)&sAl[wm + m * 16 + fr][fkb];
        }
#pragma unroll
        for (int n2 = 0; n2 < 4; ++n2) {
            fbh[n2] = *(const s8v*)&sBh[wn + n2 * 16 + fr][fkb];
            fbl[n2] = *(const s8v*)&sBl[wn + n2 * 16 + fr][fkb];
        }
#pragma unroll
        for (int m = 0; m < 4; ++m)
#pragma unroll
            for (int n2 = 0; n2 < 4; ++n2) {
                acc[m][n2] = MFMA16(fah[m], fbh[n2], acc[m][n2]);
                acc[m][n2] = MFMA16(fah[m], fbl[n2], acc[m][n2]);
                acc[m][n2] = MFMA16(fal[m], fbh[n2], acc[m][n2]);
            }
        __syncthreads();
    }

    const int rg = (lane >> 4) * 4;
#pragma unroll
    for (int m = 0; m < 4; ++m)
#pragma unroll
        for (int n2 = 0; n2 < 4; ++n2)
#pragma unroll
            for (int r = 0; r < 4; ++r)
                C[(size_t)(m0 + wm + m * 16 + rg + r) * LDC + (n0 + wn + n2 * 16 + fr)] =
                    f2bf(acc[m][n2][r]);
}

// ---------------------------------------------------------------------------
// Stage 1.5: Vt[n][head][e][token] = V[n][token][head][e]  (bf16)
// ---------------------------------------------------------------------------
__global__ __launch_bounds__(256) void vtrans(const unsigned short* __restrict__ qkv,
                                              unsigned short* __restrict__ vt) {
    __shared__ unsigned short t[64][72];
    const int tt = blockIdx.x, head = blockIdx.y, n = blockIdx.z;
    const int tid = threadIdx.x;
#pragma unroll
    for (int i = 0; i < 2; ++i) {
        const int el = i * 2048 + tid * 8;
        const int tr = el >> 6, c = el & 63;
        s8v v = *(const s8v*)(qkv + (size_t)(n * 2304 + tt * 64 + tr) * 2304 + 1536 + head * 64 + c);
        *(s8v*)&t[tr][c] = v;
    }
    __syncthreads();
#pragma unroll
    for (int i = 0; i < 2; ++i) {
        const int el = i * 2048 + tid * 8;
        const int er = el >> 6, tk = el & 63;
        s8v w;
#pragma unroll
        for (int j = 0; j < 8; ++j) w[j] = (short)t[tk + j][er];
        *(s8v*)(vt + (size_t)((n * 12 + head) * 64 + er) * 2304 + tt * 64 + tk) = w;
    }
}

// ---------------------------------------------------------------------------
// Stage 2: neighborhood attention. Block = (qx, head, n), 3 waves x 16 queries.
// ---------------------------------------------------------------------------
__global__ __launch_bounds__(192) void attn_kernel(const unsigned short* __restrict__ qkv,
                                                   const unsigned short* __restrict__ vt,
                                                   unsigned short* __restrict__ o,
                                                   const int* __restrict__ ksp) {
    __shared__ unsigned short pbuf[3][16][72];
    const int lane = threadIdx.x & 63, wv = threadIdx.x >> 6;
    const int qx = blockIdx.x, head = blockIdx.y, n = blockIdx.z;
    const int fr = lane & 15, fg = lane >> 4;
    const int KS = *ksp;

#pragma unroll
    for (int i = 0; i < 4; ++i) pbuf[wv][fr][48 + fg * 4 + i] = 0;

    const int qtok = qx * 48 + wv * 16 + fr;
    const unsigned short* qrow = qkv + (size_t)(n * 2304 + qtok) * 2304 + head * 64;
    const s8v qa0 = *(const s8v*)(qrow + fg * 8);
    const s8v qa1 = *(const s8v*)(qrow + 32 + fg * 8);

    f32x4 Oacc[4];
#pragma unroll
    for (int e = 0; e < 4; ++e) Oacc[e] = (f32x4){0.f, 0.f, 0.f, 0.f};
    float mrow[4] = {-1e30f, -1e30f, -1e30f, -1e30f};
    float lrow[4] = {0.f, 0.f, 0.f, 0.f};

    const int kx0 = (qx - KS) > 0 ? (qx - KS) : 0;
    const int kx1 = (qx + KS) < 47 ? (qx + KS) : 47;

    for (int kx = kx0; kx <= kx1; ++kx) {
        f32x4 s[3];
#pragma unroll
        for (int nt = 0; nt < 3; ++nt) {
            const int ktok = kx * 48 + nt * 16 + fr;
            const unsigned short* krow = qkv + (size_t)(n * 2304 + ktok) * 2304 + 768 + head * 64;
            s8v kb0 = *(const s8v*)(krow + fg * 8);
            s8v kb1 = *(const s8v*)(krow + 32 + fg * 8);
            f32x4 z = (f32x4){0.f, 0.f, 0.f, 0.f};
            z = MFMA16(qa0, kb0, z);
            z = MFMA16(qa1, kb1, z);
            s[nt] = z;
        }
        float vmax[4] = {-1e30f, -1e30f, -1e30f, -1e30f};
#pragma unroll
        for (int nt = 0; nt < 3; ++nt) {
            const int ky = nt * 16 + fr;
#pragma unroll
            for (int r = 0; r < 4; ++r) {
                const int qy = wv * 16 + fg * 4 + r;
                float v = s[nt][r] * 0.125f;
                const int dy = ky - qy;
                if (dy < -KS || dy > KS) v = -1e30f;
                s[nt][r] = v;
                vmax[r] = fmaxf(vmax[r], v);
            }
        }
#pragma unroll
        for (int d = 1; d < 16; d <<= 1)
#pragma unroll
            for (int r = 0; r < 4; ++r) vmax[r] = fmaxf(vmax[r], __shfl_xor(vmax[r], d));

        float sf[4], rs[4];
#pragma unroll
        for (int r = 0; r < 4; ++r) {
            const float mn = fmaxf(mrow[r], vmax[r]);
            sf[r] = __expf(mrow[r] - mn);
            mrow[r] = mn;
        }
#pragma unroll
        for (int nt = 0; nt < 3; ++nt)
#pragma unroll
            for (int r = 0; r < 4; ++r) s[nt][r] = __expf(s[nt][r] - mrow[r]);
#pragma unroll
        for (int r = 0; r < 4; ++r) rs[r] = s[0][r] + s[1][r] + s[2][r];
#pragma unroll
        for (int d = 1; d < 16; d <<= 1)
#pragma unroll
            for (int r = 0; r < 4; ++r) rs[r] += __shfl_xor(rs[r], d);
#pragma unroll
        for (int r = 0; r < 4; ++r) lrow[r] = lrow[r] * sf[r] + rs[r];
#pragma unroll
        for (int e = 0; e < 4; ++e)
#pragma unroll
            for (int r = 0; r < 4; ++r) Oacc[e][r] *= sf[r];

#pragma unroll
        for (int nt = 0; nt < 3; ++nt)
#pragma unroll
            for (int r = 0; r < 4; ++r)
                pbuf[wv][fg * 4 + r][nt * 16 + fr] = f2bf(s[nt][r]);
        __syncthreads();

        const s8v pa0 = *(const s8v*)&pbuf[wv][fr][fg * 8];
        const s8v pa1 = *(const s8v*)&pbuf[wv][fr][32 + fg * 8];

        const unsigned short* vbase = vt + (size_t)((n * 12 + head) * 64) * 2304 + kx * 48;
#pragma unroll
        for (int et = 0; et < 4; ++et) {
            const unsigned short* vrow = vbase + (size_t)(et * 16 + fr) * 2304;
            s8v vb0 = *(const s8v*)(vrow + fg * 8);
            s8v vb1 = *(const s8v*)(vrow + 32 + fg * 8);
            Oacc[et] = MFMA16(pa0, vb0, Oacc[et]);
            Oacc[et] = MFMA16(pa1, vb1, Oacc[et]);
        }
        __syncthreads();
    }

    unsigned short* obase = o + (size_t)(n * 2304 + qx * 48 + wv * 16) * 768 + head * 64;
#pragma unroll
    for (int r = 0; r < 4; ++r) {
        const float inv = 1.f / lrow[r];
#pragma unroll
        for (int et = 0; et < 4; ++et)
            obase[(size_t)(fg * 4 + r) * 768 + et * 16 + fr] = f2bf(Oacc[et][r] * inv);
    }
}

// ---------------------------------------------------------------------------
// Stage 3: out = o @ w_out^T (A bf16 [4608,768], B bf16 [768,768], C fp32)
// m97 structure: global_load_lds staging, 16 MFMA / K-step.
// ---------------------------------------------------------------------------
__global__ __launch_bounds__(256) void gemm_out2(const unsigned short* __restrict__ A,
                                                 const unsigned short* __restrict__ B,
                                                 float* __restrict__ C) {
    constexpr int LD = 768, LDC = 768;
    __shared__ __align__(16) unsigned short sA[128][32], sB[128][32];
    const int tid = threadIdx.x, lane = tid & 63, wv = tid >> 6;
    const int wm = (wv >> 1) * 64, wn = (wv & 1) * 64;
    const int m0 = blockIdx.y * 128, n0 = blockIdx.x * 128;
    const int fr = lane & 15, fkb = (lane >> 4) * 8;

    const int srow = tid >> 2, scol = (tid & 3) * 8;
    const unsigned short* gA = A + (size_t)(m0 + srow) * LD + scol;
    const unsigned short* gB = B + (size_t)(n0 + srow) * LD + scol;

    f32x4 acc[4][4];
#pragma unroll
    for (int m = 0; m < 4; ++m)
#pragma unroll
        for (int n2 = 0; n2 < 4; ++n2) acc[m][n2] = (f32x4){0.f, 0.f, 0.f, 0.f};

    for (int kt = 0; kt < 24; ++kt) {
        const int k0 = kt * 32;
        gload16(&sA[srow][scol],      gA + k0);
        gload16(&sA[64 + srow][scol], gA + 64 * LD + k0);
        gload16(&sB[srow][scol],      gB + k0);
        gload16(&sB[64 + srow][scol], gB + 64 * LD + k0);
        __syncthreads();

        s8v fa[4], fb[4];
#pragma unroll
        for (int m = 0; m < 4; ++m) fa[m] = *(const s8v*)&sA[wm + m * 16 + fr][fkb];
#pragma unroll
        for (int n2 = 0; n2 < 4; ++n2) fb[n2] = *(const s8v*)&sB[wn + n2 * 16 + fr][fkb];
#pragma unroll
        for (int m = 0; m < 4; ++m)
#pragma unroll
            for (int n2 = 0; n2 < 4; ++n2) acc[m][n2] = MFMA16(fa[m], fb[n2], acc[m][n2]);
        __syncthreads();
    }

    const int rg = (lane >> 4) * 4;
#pragma unroll
    for (int m = 0; m < 4; ++m)
#pragma unroll
        for (int n2 = 0; n2 < 4; ++n2)
#pragma unroll
            for (int r = 0; r < 4; ++r)
                C[(size_t)(m0 + wm + m * 16 + rg + r) * LDC + (n0 + wn + n2 * 16 + fr)] =
                    acc[m][n2][r];
}

// ---------------------------------------------------------------------------
extern "C" void kernel_launch(void* const* d_in, const int* in_sizes, int n_in,
                              void* d_out, int out_size, void* d_ws, size_t ws_size,
                              hipStream_t stream) {
    const float* x     = (const float*)d_in[0];
    const float* w_qkv = (const float*)d_in[1];
    const float* w_out = (const float*)d_in[2];
    const int*   ksp   = (const int*)d_in[3];
    float* out = (float*)d_out;

    char* ws = (char*)d_ws;
    unsigned short* qkv = (unsigned short*)(ws);                 // 21,233,664 B
    unsigned short* vt  = (unsigned short*)(ws + 21233664);      //  7,077,888 B
    unsigned short* o   = (unsigned short*)(ws + 28311552);      //  7,077,888 B
    unsigned short* xh  = (unsigned short*)(ws + 35389440);      //  7,077,888 B
    unsigned short* xl  = (unsigned short*)(ws + 42467328);      //  7,077,888 B
    unsigned short* wqh = (unsigned short*)(ws + 49545216);      //  3,538,944 B
    unsigned short* wql = (unsigned short*)(ws + 53084160);      //  3,538,944 B
    unsigned short* woh = (unsigned short*)(ws + 56623104);      //  1,179,648 B

    split_hl<<<dim3(1728), 256, 0, stream>>>(x, xh, xl, 442368);        // 4608*768/8
    split_hl<<<dim3(864),  256, 0, stream>>>(w_qkv, wqh, wql, 221184);  // 2304*768/8
    conv_bf16<<<dim3(288), 256, 0, stream>>>(w_out, woh, 73728);        // 768*768/8

    gemm_qkv2<<<dim3(18, 36), 256, 0, stream>>>(xh, xl, wqh, wql, qkv);
    vtrans<<<dim3(36, 12, 2), 256, 0, stream>>>(qkv, vt);
    attn_kernel<<<dim3(48, 12, 2), 192, 0, stream>>>(qkv, vt, o, ksp);
    gemm_out2<<<dim3(6, 36), 256, 0, stream>>>(o, woh, out);
}

// Round 3
// 168.550 us; speedup vs baseline: 1.3252x; 1.1356x over previous
//
#include <hip/hip_runtime.h>

using f32x4 = __attribute__((ext_vector_type(4))) float;
using s8v   = __attribute__((ext_vector_type(8))) short;
using us4v  = __attribute__((ext_vector_type(4))) unsigned short;

__device__ inline unsigned short f2bf(float f) {
    union { float fl; unsigned int u; } v; v.fl = f;
    unsigned int u = v.u;
    return (unsigned short)((u + 0x7fffu + ((u >> 16) & 1u)) >> 16);
}
__device__ inline float bf2f(unsigned short h) {
    union { unsigned int u; float fl; } v; v.u = ((unsigned int)h) << 16;
    return v.fl;
}

#define MFMA16(a, b, c) __builtin_amdgcn_mfma_f32_16x16x32_bf16((a), (b), (c), 0, 0, 0)

typedef __attribute__((address_space(3))) unsigned int lds_uint;
typedef const __attribute__((address_space(1))) unsigned int glb_uint;
__device__ inline void gload16(void* l, const void* g) {
    __builtin_amdgcn_global_load_lds((glb_uint*)g, (lds_uint*)l, 16, 0, 0);
}

// ---------------------------------------------------------------------------
// Split fp32 -> bf16 hi + bf16 lo (residual). 8 elements / thread.
// ---------------------------------------------------------------------------
__global__ __launch_bounds__(256) void split_hl(const float* __restrict__ in,
                                                unsigned short* __restrict__ hi,
                                                unsigned short* __restrict__ lo,
                                                int n8) {
    const int i = blockIdx.x * blockDim.x + threadIdx.x;
    if (i >= n8) return;
    const float4 a = *(const float4*)(in + (size_t)i * 8);
    const float4 b = *(const float4*)(in + (size_t)i * 8 + 4);
    s8v h, l;
    unsigned short t;
    t = f2bf(a.x); h[0] = t; l[0] = f2bf(a.x - bf2f(t));
    t = f2bf(a.y); h[1] = t; l[1] = f2bf(a.y - bf2f(t));
    t = f2bf(a.z); h[2] = t; l[2] = f2bf(a.z - bf2f(t));
    t = f2bf(a.w); h[3] = t; l[3] = f2bf(a.w - bf2f(t));
    t = f2bf(b.x); h[4] = t; l[4] = f2bf(b.x - bf2f(t));
    t = f2bf(b.y); h[5] = t; l[5] = f2bf(b.y - bf2f(t));
    t = f2bf(b.z); h[6] = t; l[6] = f2bf(b.z - bf2f(t));
    t = f2bf(b.w); h[7] = t; l[7] = f2bf(b.w - bf2f(t));
    *(s8v*)(hi + (size_t)i * 8) = h;
    *(s8v*)(lo + (size_t)i * 8) = l;
}

__global__ __launch_bounds__(256) void conv_bf16(const float* __restrict__ in,
                                                 unsigned short* __restrict__ hi, int n8) {
    const int i = blockIdx.x * blockDim.x + threadIdx.x;
    if (i >= n8) return;
    const float4 a = *(const float4*)(in + (size_t)i * 8);
    const float4 b = *(const float4*)(in + (size_t)i * 8 + 4);
    s8v h;
    h[0] = f2bf(a.x); h[1] = f2bf(a.y); h[2] = f2bf(a.z); h[3] = f2bf(a.w);
    h[4] = f2bf(b.x); h[5] = f2bf(b.y); h[6] = f2bf(b.z); h[7] = f2bf(b.w);
    *(s8v*)(hi + (size_t)i * 8) = h;
}

// ---------------------------------------------------------------------------
// Stage 1: qkv = x @ w_qkv^T, 3-term split bf16 MFMA (m97 structure).
// ---------------------------------------------------------------------------
__global__ __launch_bounds__(256) void gemm_qkv2(const unsigned short* __restrict__ Ah,
                                                 const unsigned short* __restrict__ Al,
                                                 const unsigned short* __restrict__ Bh,
                                                 const unsigned short* __restrict__ Bl,
                                                 unsigned short* __restrict__ C) {
    constexpr int LD = 768, LDC = 2304;
    __shared__ __align__(16) unsigned short sAh[128][32], sAl[128][32];
    __shared__ __align__(16) unsigned short sBh[128][32], sBl[128][32];
    const int tid = threadIdx.x, lane = tid & 63, wv = tid >> 6;
    const int wm = (wv >> 1) * 64, wn = (wv & 1) * 64;
    const int m0 = blockIdx.y * 128, n0 = blockIdx.x * 128;
    const int fr = lane & 15, fkb = (lane >> 4) * 8;

    const int srow = tid >> 2, scol = (tid & 3) * 8;
    const unsigned short* gAh = Ah + (size_t)(m0 + srow) * LD + scol;
    const unsigned short* gAl = Al + (size_t)(m0 + srow) * LD + scol;
    const unsigned short* gBh = Bh + (size_t)(n0 + srow) * LD + scol;
    const unsigned short* gBl = Bl + (size_t)(n0 + srow) * LD + scol;

    f32x4 acc[4][4];
#pragma unroll
    for (int m = 0; m < 4; ++m)
#pragma unroll
        for (int n2 = 0; n2 < 4; ++n2) acc[m][n2] = (f32x4){0.f, 0.f, 0.f, 0.f};

    for (int kt = 0; kt < 24; ++kt) {
        const int k0 = kt * 32;
        gload16(&sAh[srow][scol],      gAh + k0);
        gload16(&sAh[64 + srow][scol], gAh + 64 * LD + k0);
        gload16(&sAl[srow][scol],      gAl + k0);
        gload16(&sAl[64 + srow][scol], gAl + 64 * LD + k0);
        gload16(&sBh[srow][scol],      gBh + k0);
        gload16(&sBh[64 + srow][scol], gBh + 64 * LD + k0);
        gload16(&sBl[srow][scol],      gBl + k0);
        gload16(&sBl[64 + srow][scol], gBl + 64 * LD + k0);
        __syncthreads();

        s8v fah[4], fal[4], fbh[4], fbl[4];
#pragma unroll
        for (int m = 0; m < 4; ++m) {
            fah[m] = *(const s8v*)&sAh[wm + m * 16 + fr][fkb];
            fal[m] = *(const s8v*)&sAl[wm + m * 16 + fr][fkb];
        }
#pragma unroll
        for (int n2 = 0; n2 < 4; ++n2) {
            fbh[n2] = *(const s8v*)&sBh[wn + n2 * 16 + fr][fkb];
            fbl[n2] = *(const s8v*)&sBl[wn + n2 * 16 + fr][fkb];
        }
#pragma unroll
        for (int m = 0; m < 4; ++m)
#pragma unroll
            for (int n2 = 0; n2 < 4; ++n2) {
                acc[m][n2] = MFMA16(fah[m], fbh[n2], acc[m][n2]);
                acc[m][n2] = MFMA16(fah[m], fbl[n2], acc[m][n2]);
                acc[m][n2] = MFMA16(fal[m], fbh[n2], acc[m][n2]);
            }
        __syncthreads();
    }

    const int rg = (lane >> 4) * 4;
#pragma unroll
    for (int m = 0; m < 4; ++m)
#pragma unroll
        for (int n2 = 0; n2 < 4; ++n2)
#pragma unroll
            for (int r = 0; r < 4; ++r)
                C[(size_t)(m0 + wm + m * 16 + rg + r) * LDC + (n0 + wn + n2 * 16 + fr)] =
                    f2bf(acc[m][n2][r]);
}

// ---------------------------------------------------------------------------
// Stage 1.5: Vt[n][head][e][token] = V[n][token][head][e]  (bf16)
// ---------------------------------------------------------------------------
__global__ __launch_bounds__(256) void vtrans(const unsigned short* __restrict__ qkv,
                                              unsigned short* __restrict__ vt) {
    __shared__ unsigned short t[64][72];
    const int tt = blockIdx.x, head = blockIdx.y, n = blockIdx.z;
    const int tid = threadIdx.x;
#pragma unroll
    for (int i = 0; i < 2; ++i) {
        const int el = i * 2048 + tid * 8;
        const int tr = el >> 6, c = el & 63;
        s8v v = *(const s8v*)(qkv + (size_t)(n * 2304 + tt * 64 + tr) * 2304 + 1536 + head * 64 + c);
        *(s8v*)&t[tr][c] = v;
    }
    __syncthreads();
#pragma unroll
    for (int i = 0; i < 2; ++i) {
        const int el = i * 2048 + tid * 8;
        const int er = el >> 6, tk = el & 63;
        s8v w;
#pragma unroll
        for (int j = 0; j < 8; ++j) w[j] = (short)t[tk + j][er];
        *(s8v*)(vt + (size_t)((n * 12 + head) * 64 + er) * 2304 + tt * 64 + tk) = w;
    }
}

// ---------------------------------------------------------------------------
// Stage 2: neighborhood attention, per-wave blocks, swapped QK^T, XCD swizzle.
// grid = 3456 blocks x 64 threads; block b: xcd=b&7 owns qx in [xcd*6, xcd*6+6)
// ---------------------------------------------------------------------------
__global__ __launch_bounds__(64) void attn_kernel(const unsigned short* __restrict__ qkv,
                                                  const unsigned short* __restrict__ vt,
                                                  unsigned short* __restrict__ o,
                                                  const int* __restrict__ ksp) {
    __shared__ __align__(16) unsigned short pbuf[16][72];
    const int lane = threadIdx.x & 63;
    const int fr = lane & 15, fg = lane >> 4;

    // swizzled decode: per-XCD contiguous qx chunk, (head,n) fastest
    const int b = blockIdx.x;
    const int xcd = b & 7, w = b >> 3;      // w in [0,432)
    const int qxo = w / 72, rem = w % 72;
    const int hn = rem / 3, wv = rem % 3;
    const int head = hn >> 1, n = hn & 1;
    const int qx = xcd * 6 + qxo;
    const int KS = *ksp;

    // zero P pad columns 48..63 (read only by 2-chunk waves)
    *(unsigned int*)&pbuf[fr][48 + fg * 4]     = 0u;
    *(unsigned int*)&pbuf[fr][48 + fg * 4 + 2] = 0u;

    const int qy = wv * 16 + fr;            // this lane's query (col in image row)
    const unsigned short* qrow = qkv + (size_t)(n * 2304 + qx * 48 + qy) * 2304 + head * 64;
    const s8v qa0 = *(const s8v*)(qrow + fg * 8);
    const s8v qa1 = *(const s8v*)(qrow + 32 + fg * 8);

    // active key tiles for this wave's 16 queries
    int nt0 = (wv * 16 - KS) >> 4;      if (nt0 < 0) nt0 = 0;
    int nt1 = (wv * 16 + 15 + KS) >> 4; if (nt1 > 2) nt1 = 2;
    const int nc = ((nt1 - nt0 + 1) * 16 + 31) >> 5;   // 32-key PV chunks (1 or 2)
    const int cb = nt0 * 16;

    f32x4 Oacc[4];
#pragma unroll
    for (int e = 0; e < 4; ++e) Oacc[e] = (f32x4){0.f, 0.f, 0.f, 0.f};
    float mrow = -1e30f, lrow = 0.f;

    const int kx0 = (qx - KS) > 0 ? (qx - KS) : 0;
    const int kx1 = (qx + KS) < 47 ? (qx + KS) : 47;

    const unsigned short* kbase = qkv + (size_t)(n * 2304) * 2304 + 768 + head * 64;
    const unsigned short* vbase = vt + (size_t)((n * 12 + head) * 64) * 2304;

    auto issueK = [&](s8v (&kb)[3][2], int kx) {
#pragma unroll
        for (int nt = 0; nt < 3; ++nt)
            if (nt >= nt0 && nt <= nt1) {
                const unsigned short* kr = kbase + (size_t)(kx * 48 + nt * 16 + fr) * 2304;
                kb[nt][0] = *(const s8v*)(kr + fg * 8);
                kb[nt][1] = *(const s8v*)(kr + 32 + fg * 8);
            }
    };

    auto compute = [&](s8v (&kb)[3][2], s8v (&kbN)[3][2], int kx, bool haveN) {
        // issue V loads early (latency hides under softmax)
        s8v vb[2][4];
#pragma unroll
        for (int ci = 0; ci < 2; ++ci)
            if (ci < nc)
#pragma unroll
                for (int et = 0; et < 4; ++et) {
                    const unsigned short* vr =
                        vbase + (size_t)(et * 16 + fr) * 2304 + kx * 48 + cb + ci * 32;
                    vb[ci][et] = *(const s8v*)(vr + fg * 8);
                }
        // QK^T (swapped: S^T[key][query]) — lane holds keys fg*4+r of query fr
        f32x4 s[3];
#pragma unroll
        for (int nt = 0; nt < 3; ++nt)
            if (nt >= nt0 && nt <= nt1) {
                f32x4 z = (f32x4){0.f, 0.f, 0.f, 0.f};
                z = MFMA16(kb[nt][0], qa0, z);
                z = MFMA16(kb[nt][1], qa1, z);
                s[nt] = z;
            }
        // prefetch next row's K while we do softmax
        if (haveN) issueK(kbN, kx + 1);

        // mask + per-lane max
        float vmax = -1e30f;
#pragma unroll
        for (int nt = 0; nt < 3; ++nt)
            if (nt >= nt0 && nt <= nt1)
#pragma unroll
                for (int r = 0; r < 4; ++r) {
                    const int ky = nt * 16 + fg * 4 + r;
                    float v = s[nt][r] * 0.125f;
                    const int dy = ky - qy;
                    if (dy < -KS || dy > KS) v = -1e30f;
                    s[nt][r] = v;
                    vmax = fmaxf(vmax, v);
                }
        vmax = fmaxf(vmax, __shfl_xor(vmax, 16));
        vmax = fmaxf(vmax, __shfl_xor(vmax, 32));

        const float mn = fmaxf(mrow, vmax);
        const float sf = __expf(mrow - mn);
        mrow = mn;
        float rs = 0.f;
#pragma unroll
        for (int nt = 0; nt < 3; ++nt)
            if (nt >= nt0 && nt <= nt1)
#pragma unroll
                for (int r = 0; r < 4; ++r) {
                    const float p = __expf(s[nt][r] - mn);
                    s[nt][r] = p;
                    rs += p;
                }
        rs += __shfl_xor(rs, 16);
        rs += __shfl_xor(rs, 32);
        lrow = lrow * sf + rs;

        // rescale O (rows are queries fg*4+r -> fetch sf from lane fg*4+r)
        float sfr[4];
#pragma unroll
        for (int r = 0; r < 4; ++r) sfr[r] = __shfl(sf, fg * 4 + r);
#pragma unroll
        for (int et = 0; et < 4; ++et)
#pragma unroll
            for (int r = 0; r < 4; ++r) Oacc[et][r] *= sfr[r];

        // P -> LDS (packed pairs), row = query fr
#pragma unroll
        for (int nt = 0; nt < 3; ++nt)
            if (nt >= nt0 && nt <= nt1)
#pragma unroll
                for (int i = 0; i < 2; ++i) {
                    const unsigned int dw = (unsigned int)f2bf(s[nt][2 * i]) |
                                            ((unsigned int)f2bf(s[nt][2 * i + 1]) << 16);
                    *(unsigned int*)&pbuf[fr][nt * 16 + fg * 4 + 2 * i] = dw;
                }
        asm volatile("s_waitcnt lgkmcnt(0)" ::: "memory");
        __builtin_amdgcn_sched_barrier(0);

        // PV per 32-key chunk
#pragma unroll
        for (int ci = 0; ci < 2; ++ci)
            if (ci < nc) {
                const s8v pa = *(const s8v*)&pbuf[fr][cb + ci * 32 + fg * 8];
#pragma unroll
                for (int et = 0; et < 4; ++et)
                    Oacc[et] = MFMA16(pa, vb[ci][et], Oacc[et]);
            }
    };

    s8v kbA[3][2], kbB[3][2];
    issueK(kbA, kx0);
    int kx = kx0;
    while (true) {
        const bool hA = (kx + 1 <= kx1);
        compute(kbA, kbB, kx, hA);
        if (!hA) break;
        ++kx;
        const bool hB = (kx + 1 <= kx1);
        compute(kbB, kbA, kx, hB);
        if (!hB) break;
        ++kx;
    }

    // epilogue
    const float linv = 1.f / lrow;
    float li[4];
#pragma unroll
    for (int r = 0; r < 4; ++r) li[r] = __shfl(linv, fg * 4 + r);
    unsigned short* ob = o + (size_t)(n * 2304 + qx * 48 + wv * 16) * 768 + head * 64;
#pragma unroll
    for (int et = 0; et < 4; ++et)
#pragma unroll
        for (int r = 0; r < 4; ++r)
            ob[(size_t)(fg * 4 + r) * 768 + et * 16 + fr] = f2bf(Oacc[et][r] * li[r]);
}

// ---------------------------------------------------------------------------
// Stage 3: out = o @ w_out^T (A bf16 [4608,768], B bf16 [768,768], C fp32)
// ---------------------------------------------------------------------------
__global__ __launch_bounds__(256) void gemm_out2(const unsigned short* __restrict__ A,
                                                 const unsigned short* __restrict__ B,
                                                 float* __restrict__ C) {
    constexpr int LD = 768, LDC = 768;
    __shared__ __align__(16) unsigned short sA[128][32], sB[128][32];
    const int tid = threadIdx.x, lane = tid & 63, wv = tid >> 6;
    const int wm = (wv >> 1) * 64, wn = (wv & 1) * 64;
    const int m0 = blockIdx.y * 128, n0 = blockIdx.x * 128;
    const int fr = lane & 15, fkb = (lane >> 4) * 8;

    const int srow = tid >> 2, scol = (tid & 3) * 8;
    const unsigned short* gA = A + (size_t)(m0 + srow) * LD + scol;
    const unsigned short* gB = B + (size_t)(n0 + srow) * LD + scol;

    f32x4 acc[4][4];
#pragma unroll
    for (int m = 0; m < 4; ++m)
#pragma unroll
        for (int n2 = 0; n2 < 4; ++n2) acc[m][n2] = (f32x4){0.f, 0.f, 0.f, 0.f};

    for (int kt = 0; kt < 24; ++kt) {
        const int k0 = kt * 32;
        gload16(&sA[srow][scol],      gA + k0);
        gload16(&sA[64 + srow][scol], gA + 64 * LD + k0);
        gload16(&sB[srow][scol],      gB + k0);
        gload16(&sB[64 + srow][scol], gB + 64 * LD + k0);
        __syncthreads();

        s8v fa[4], fb[4];
#pragma unroll
        for (int m = 0; m < 4; ++m) fa[m] = *(const s8v*)&sA[wm + m * 16 + fr][fkb];
#pragma unroll
        for (int n2 = 0; n2 < 4; ++n2) fb[n2] = *(const s8v*)&sB[wn + n2 * 16 + fr][fkb];
#pragma unroll
        for (int m = 0; m < 4; ++m)
#pragma unroll
            for (int n2 = 0; n2 < 4; ++n2) acc[m][n2] = MFMA16(fa[m], fb[n2], acc[m][n2]);
        __syncthreads();
    }

    const int rg = (lane >> 4) * 4;
#pragma unroll
    for (int m = 0; m < 4; ++m)
#pragma unroll
        for (int n2 = 0; n2 < 4; ++n2)
#pragma unroll
            for (int r = 0; r < 4; ++r)
                C[(size_t)(m0 + wm + m * 16 + rg + r) * LDC + (n0 + wn + n2 * 16 + fr)] =
                    acc[m][n2][r];
}

// ---------------------------------------------------------------------------
extern "C" void kernel_launch(void* const* d_in, const int* in_sizes, int n_in,
                              void* d_out, int out_size, void* d_ws, size_t ws_size,
                              hipStream_t stream) {
    const float* x     = (const float*)d_in[0];
    const float* w_qkv = (const float*)d_in[1];
    const float* w_out = (const float*)d_in[2];
    const int*   ksp   = (const int*)d_in[3];
    float* out = (float*)d_out;

    char* ws = (char*)d_ws;
    unsigned short* qkv = (unsigned short*)(ws);                 // 21,233,664 B
    unsigned short* vt  = (unsigned short*)(ws + 21233664);      //  7,077,888 B (+4KB slack)
    unsigned short* o   = (unsigned short*)(ws + 28315648);      //  7,077,888 B
    unsigned short* xh  = (unsigned short*)(ws + 35393536);      //  7,077,888 B
    unsigned short* xl  = (unsigned short*)(ws + 42471424);      //  7,077,888 B
    unsigned short* wqh = (unsigned short*)(ws + 49549312);      //  3,538,944 B
    unsigned short* wql = (unsigned short*)(ws + 53088256);      //  3,538,944 B
    unsigned short* woh = (unsigned short*)(ws + 56627200);      //  1,179,648 B

    split_hl<<<dim3(1728), 256, 0, stream>>>(x, xh, xl, 442368);
    split_hl<<<dim3(864),  256, 0, stream>>>(w_qkv, wqh, wql, 221184);
    conv_bf16<<<dim3(288), 256, 0, stream>>>(w_out, woh, 73728);

    gemm_qkv2<<<dim3(18, 36), 256, 0, stream>>>(xh, xl, wqh, wql, qkv);
    vtrans<<<dim3(36, 12, 2), 256, 0, stream>>>(qkv, vt);
    attn_kernel<<<dim3(3456), 64, 0, stream>>>(qkv, vt, o, ksp);
    gemm_out2<<<dim3(6, 36), 256, 0, stream>>>(o, woh, out);
}

// Round 4
// 142.608 us; speedup vs baseline: 1.5663x; 1.1819x over previous
//
#include <hip/hip_runtime.h>

using f32x4 = __attribute__((ext_vector_type(4))) float;
using h8v   = __attribute__((ext_vector_type(8))) _Float16;
using s8v   = __attribute__((ext_vector_type(8))) short;

#define MFMAH(a, b, c) __builtin_amdgcn_mfma_f32_16x16x32_f16((a), (b), (c), 0, 0, 0)

typedef __attribute__((address_space(3))) unsigned int lds_uint;
typedef const __attribute__((address_space(1))) unsigned int glb_uint;
__device__ inline void gload16(void* l, const void* g) {
    __builtin_amdgcn_global_load_lds((glb_uint*)g, (lds_uint*)l, 16, 0, 0);
}

// ---------------------------------------------------------------------------
// fp32 -> fp16, 8 elements / thread
// ---------------------------------------------------------------------------
__global__ __launch_bounds__(256) void conv_fp16(const float* __restrict__ in,
                                                 _Float16* __restrict__ out, int n8) {
    const int i = blockIdx.x * blockDim.x + threadIdx.x;
    if (i >= n8) return;
    const float4 a = *(const float4*)(in + (size_t)i * 8);
    const float4 b = *(const float4*)(in + (size_t)i * 8 + 4);
    h8v h;
    h[0] = (_Float16)a.x; h[1] = (_Float16)a.y; h[2] = (_Float16)a.z; h[3] = (_Float16)a.w;
    h[4] = (_Float16)b.x; h[5] = (_Float16)b.y; h[6] = (_Float16)b.z; h[7] = (_Float16)b.w;
    *(h8v*)(out + (size_t)i * 8) = h;
}

// ---------------------------------------------------------------------------
// Stage 1: qkv = x @ w_qkv^T  (fp16 in, fp16 out), m97 structure, XCD swizzle
// grid 648 = 8 * 81;  M=4608 (by 36), N=2304 (bx 18)
// ---------------------------------------------------------------------------
__global__ __launch_bounds__(256) void gemm_qkv_f16(const _Float16* __restrict__ A,
                                                    const _Float16* __restrict__ B,
                                                    _Float16* __restrict__ C) {
    constexpr int LD = 768, LDC = 2304;
    __shared__ __align__(16) _Float16 sA[128][32], sB[128][32];
    const int b = blockIdx.x;
    const int sb = (b & 7) * 81 + (b >> 3);
    const int bx = sb % 18, by = sb / 18;
    const int m0 = by * 128, n0 = bx * 128;
    const int tid = threadIdx.x, lane = tid & 63, wv = tid >> 6;
    const int wm = (wv >> 1) * 64, wn = (wv & 1) * 64;
    const int fr = lane & 15, fkb = (lane >> 4) * 8;

    const int srow = tid >> 2, scol = (tid & 3) * 8;
    const _Float16* gA = A + (size_t)(m0 + srow) * LD + scol;
    const _Float16* gB = B + (size_t)(n0 + srow) * LD + scol;

    f32x4 acc[4][4];
#pragma unroll
    for (int m = 0; m < 4; ++m)
#pragma unroll
        for (int n2 = 0; n2 < 4; ++n2) acc[m][n2] = (f32x4){0.f, 0.f, 0.f, 0.f};

    for (int kt = 0; kt < 24; ++kt) {
        const int k0 = kt * 32;
        gload16(&sA[srow][scol],      gA + k0);
        gload16(&sA[64 + srow][scol], gA + 64 * LD + k0);
        gload16(&sB[srow][scol],      gB + k0);
        gload16(&sB[64 + srow][scol], gB + 64 * LD + k0);
        __syncthreads();

        h8v fa[4], fb[4];
#pragma unroll
        for (int m = 0; m < 4; ++m) fa[m] = *(const h8v*)&sA[wm + m * 16 + fr][fkb];
#pragma unroll
        for (int n2 = 0; n2 < 4; ++n2) fb[n2] = *(const h8v*)&sB[wn + n2 * 16 + fr][fkb];
#pragma unroll
        for (int m = 0; m < 4; ++m)
#pragma unroll
            for (int n2 = 0; n2 < 4; ++n2) acc[m][n2] = MFMAH(fa[m], fb[n2], acc[m][n2]);
        __syncthreads();
    }

    const int rg = (lane >> 4) * 4;
#pragma unroll
    for (int m = 0; m < 4; ++m)
#pragma unroll
        for (int n2 = 0; n2 < 4; ++n2)
#pragma unroll
            for (int r = 0; r < 4; ++r)
                C[(size_t)(m0 + wm + m * 16 + rg + r) * LDC + (n0 + wn + n2 * 16 + fr)] =
                    (_Float16)acc[m][n2][r];
}

// ---------------------------------------------------------------------------
// Stage 1.5: Vt[n][head][e][token] = V[n][token][head][e]  (fp16 bits)
// ---------------------------------------------------------------------------
__global__ __launch_bounds__(256) void vtrans(const unsigned short* __restrict__ qkv,
                                              unsigned short* __restrict__ vt) {
    __shared__ unsigned short t[64][72];
    const int tt = blockIdx.x, head = blockIdx.y, n = blockIdx.z;
    const int tid = threadIdx.x;
#pragma unroll
    for (int i = 0; i < 2; ++i) {
        const int el = i * 2048 + tid * 8;
        const int tr = el >> 6, c = el & 63;
        s8v v = *(const s8v*)(qkv + (size_t)(n * 2304 + tt * 64 + tr) * 2304 + 1536 + head * 64 + c);
        *(s8v*)&t[tr][c] = v;
    }
    __syncthreads();
#pragma unroll
    for (int i = 0; i < 2; ++i) {
        const int el = i * 2048 + tid * 8;
        const int er = el >> 6, tk = el & 63;
        s8v w;
#pragma unroll
        for (int j = 0; j < 8; ++j) w[j] = (short)t[tk + j][er];
        *(s8v*)(vt + (size_t)((n * 12 + head) * 64 + er) * 2304 + tt * 64 + tk) = w;
    }
}

// ---------------------------------------------------------------------------
// Stage 2a: split neighborhood attention (flash-decoding, 2 splits per tile).
// grid = 6912 x 64.  b: xcd=b&7, w=b>>3: qxo=w/144, r=w%144, hn=r/6,
// r2=r%6, wv=r2>>1, sp=r2&1.  Partial per (tile t, sp): O f16[16][64] (2048B)
// + m f32[16] (@2048) + l f32[16] (@2112); 2176B per part.
// ---------------------------------------------------------------------------
__global__ __launch_bounds__(64) void attn_split(const _Float16* __restrict__ qkv,
                                                 const _Float16* __restrict__ vt,
                                                 char* __restrict__ part,
                                                 const int* __restrict__ ksp) {
    __shared__ __align__(16) _Float16 pbuf[16][72];
    const int lane = threadIdx.x & 63;
    const int fr = lane & 15, fg = lane >> 4;

    const int b = blockIdx.x;
    const int xcd = b & 7, w = b >> 3;
    const int qxo = w / 144, r0 = w % 144;
    const int hn = r0 / 6, r2 = r0 % 6;
    const int wv = r2 >> 1, sp = r2 & 1;
    const int head = hn >> 1, n = hn & 1;
    const int qx = xcd * 6 + qxo;
    const int KS = *ksp;

    // zero P pad columns 48..63
    *(unsigned int*)&pbuf[fr][48 + fg * 4]     = 0u;
    *(unsigned int*)&pbuf[fr][48 + fg * 4 + 2] = 0u;

    const int qy = wv * 16 + fr;
    const _Float16* qrow = qkv + (size_t)(n * 2304 + qx * 48 + qy) * 2304 + head * 64;
    const h8v qa0 = *(const h8v*)(qrow + fg * 8);
    const h8v qa1 = *(const h8v*)(qrow + 32 + fg * 8);

    int nt0 = (wv * 16 - KS) >> 4;      if (nt0 < 0) nt0 = 0;
    int nt1 = (wv * 16 + 15 + KS) >> 4; if (nt1 > 2) nt1 = 2;
    const int nc = ((nt1 - nt0 + 1) * 16 + 31) >> 5;
    const int cb = nt0 * 16;

    f32x4 Oacc[4];
#pragma unroll
    for (int e = 0; e < 4; ++e) Oacc[e] = (f32x4){0.f, 0.f, 0.f, 0.f};
    float mrow = -1e30f, lrow = 0.f;

    const int kx0f = (qx - KS) > 0 ? (qx - KS) : 0;
    const int kx1f = (qx + KS) < 47 ? (qx + KS) : 47;
    const int nr = kx1f - kx0f + 1, h1 = (nr + 1) >> 1;
    const int kxA = sp ? kx0f + h1 : kx0f;
    const int kxZ = sp ? kx1f : kx0f + h1 - 1;

    const _Float16* kbase = qkv + (size_t)(n * 2304) * 2304 + 768 + head * 64;
    const _Float16* vbase = vt + (size_t)((n * 12 + head) * 64) * 2304;

    auto issueK = [&](h8v (&kb)[3][2], int kx) {
#pragma unroll
        for (int nt = 0; nt < 3; ++nt)
            if (nt >= nt0 && nt <= nt1) {
                const _Float16* kr = kbase + (size_t)(kx * 48 + nt * 16 + fr) * 2304;
                kb[nt][0] = *(const h8v*)(kr + fg * 8);
                kb[nt][1] = *(const h8v*)(kr + 32 + fg * 8);
            }
    };

    auto compute = [&](h8v (&kb)[3][2], h8v (&kbN)[3][2], int kx, bool haveN) {
        h8v vb[2][4];
#pragma unroll
        for (int ci = 0; ci < 2; ++ci)
            if (ci < nc)
#pragma unroll
                for (int et = 0; et < 4; ++et) {
                    const _Float16* vr =
                        vbase + (size_t)(et * 16 + fr) * 2304 + kx * 48 + cb + ci * 32;
                    vb[ci][et] = *(const h8v*)(vr + fg * 8);
                }
        f32x4 s[3];
#pragma unroll
        for (int nt = 0; nt < 3; ++nt)
            if (nt >= nt0 && nt <= nt1) {
                f32x4 z = (f32x4){0.f, 0.f, 0.f, 0.f};
                z = MFMAH(kb[nt][0], qa0, z);
                z = MFMAH(kb[nt][1], qa1, z);
                s[nt] = z;
            }
        if (haveN) issueK(kbN, kx + 1);

        float vmax = -1e30f;
#pragma unroll
        for (int nt = 0; nt < 3; ++nt)
            if (nt >= nt0 && nt <= nt1)
#pragma unroll
                for (int r = 0; r < 4; ++r) {
                    const int ky = nt * 16 + fg * 4 + r;
                    float v = s[nt][r] * 0.125f;
                    const int dy = ky - qy;
                    if (dy < -KS || dy > KS) v = -1e30f;
                    s[nt][r] = v;
                    vmax = fmaxf(vmax, v);
                }
        vmax = fmaxf(vmax, __shfl_xor(vmax, 16));
        vmax = fmaxf(vmax, __shfl_xor(vmax, 32));

        const float mn = fmaxf(mrow, vmax);
        const float sf = __expf(mrow - mn);
        mrow = mn;
        float rs = 0.f;
#pragma unroll
        for (int nt = 0; nt < 3; ++nt)
            if (nt >= nt0 && nt <= nt1)
#pragma unroll
                for (int r = 0; r < 4; ++r) {
                    const float p = __expf(s[nt][r] - mn);
                    s[nt][r] = p;
                    rs += p;
                }
        rs += __shfl_xor(rs, 16);
        rs += __shfl_xor(rs, 32);
        lrow = lrow * sf + rs;

        float sfr[4];
#pragma unroll
        for (int r = 0; r < 4; ++r) sfr[r] = __shfl(sf, fg * 4 + r);
#pragma unroll
        for (int et = 0; et < 4; ++et)
#pragma unroll
            for (int r = 0; r < 4; ++r) Oacc[et][r] *= sfr[r];

#pragma unroll
        for (int nt = 0; nt < 3; ++nt)
            if (nt >= nt0 && nt <= nt1)
#pragma unroll
                for (int i = 0; i < 2; ++i) {
                    union { _Float16 h[2]; unsigned int u; } pk;
                    pk.h[0] = (_Float16)s[nt][2 * i];
                    pk.h[1] = (_Float16)s[nt][2 * i + 1];
                    *(unsigned int*)&pbuf[fr][nt * 16 + fg * 4 + 2 * i] = pk.u;
                }
        asm volatile("s_waitcnt lgkmcnt(0)" ::: "memory");
        __builtin_amdgcn_sched_barrier(0);

#pragma unroll
        for (int ci = 0; ci < 2; ++ci)
            if (ci < nc) {
                const h8v pa = *(const h8v*)&pbuf[fr][cb + ci * 32 + fg * 8];
#pragma unroll
                for (int et = 0; et < 4; ++et)
                    Oacc[et] = MFMAH(pa, vb[ci][et], Oacc[et]);
            }
    };

    h8v kbA[3][2], kbB[3][2];
    issueK(kbA, kxA);
    int kx = kxA;
    while (true) {
        const bool hA = (kx + 1 <= kxZ);
        compute(kbA, kbB, kx, hA);
        if (!hA) break;
        ++kx;
        const bool hB = (kx + 1 <= kxZ);
        compute(kbB, kbA, kx, hB);
        if (!hB) break;
        ++kx;
    }

    // partial epilogue (no normalization)
    const int t = ((n * 12 + head) * 48 + qx) * 3 + wv;
    char* pb = part + ((size_t)t * 2 + sp) * 2176;
    _Float16* pO = (_Float16*)pb;
    float* pm = (float*)(pb + 2048);
    float* pl = (float*)(pb + 2112);
#pragma unroll
    for (int et = 0; et < 4; ++et)
#pragma unroll
        for (int r = 0; r < 4; ++r)
            pO[(fg * 4 + r) * 64 + et * 16 + fr] = (_Float16)Oacc[et][r];
    if (fg == 0) { pm[fr] = mrow; pl[fr] = lrow; }
}

// ---------------------------------------------------------------------------
// Stage 2b: combine 2 splits -> o fp16 [n,token,768]
// grid 3456 x 64; block t; lane: q=lane>>2, ec=lane&3 (16 e's each)
// ---------------------------------------------------------------------------
__global__ __launch_bounds__(64) void attn_combine(const char* __restrict__ part,
                                                   _Float16* __restrict__ o) {
    const int t = blockIdx.x;
    const int lane = threadIdx.x & 63;
    const int q = lane >> 2, ec = lane & 3;

    const int u = t / 3, wv = t % 3;
    const int qx = u % 48, nh = u / 48;
    const int head = nh % 12, n = nh / 12;

    const char* pb1 = part + ((size_t)t * 2) * 2176;
    const char* pb2 = pb1 + 2176;
    const _Float16* pO1 = (const _Float16*)pb1;
    const _Float16* pO2 = (const _Float16*)pb2;
    const float m1 = *(const float*)(pb1 + 2048 + q * 4);
    const float l1 = *(const float*)(pb1 + 2112 + q * 4);
    const float m2 = *(const float*)(pb2 + 2048 + q * 4);
    const float l2 = *(const float*)(pb2 + 2112 + q * 4);

    const float m = fmaxf(m1, m2);
    const float a1 = __expf(m1 - m), a2 = __expf(m2 - m);
    const float inv = 1.f / (l1 * a1 + l2 * a2);
    const float w1 = a1 * inv, w2 = a2 * inv;

    const h8v x1a = *(const h8v*)(pO1 + q * 64 + ec * 16);
    const h8v x1b = *(const h8v*)(pO1 + q * 64 + ec * 16 + 8);
    const h8v x2a = *(const h8v*)(pO2 + q * 64 + ec * 16);
    const h8v x2b = *(const h8v*)(pO2 + q * 64 + ec * 16 + 8);
    h8v oa, ob;
#pragma unroll
    for (int j = 0; j < 8; ++j) {
        oa[j] = (_Float16)((float)x1a[j] * w1 + (float)x2a[j] * w2);
        ob[j] = (_Float16)((float)x1b[j] * w1 + (float)x2b[j] * w2);
    }
    const int token = n * 2304 + qx * 48 + wv * 16 + q;
    _Float16* op = o + (size_t)token * 768 + head * 64 + ec * 16;
    *(h8v*)op = oa;
    *(h8v*)(op + 8) = ob;
}

// ---------------------------------------------------------------------------
// Stage 3: out = o @ w_out^T (fp16 in, fp32 out), XCD swizzle (216 = 8*27)
// ---------------------------------------------------------------------------
__global__ __launch_bounds__(256) void gemm_out_f16(const _Float16* __restrict__ A,
                                                    const _Float16* __restrict__ B,
                                                    float* __restrict__ C) {
    constexpr int LD = 768, LDC = 768;
    __shared__ __align__(16) _Float16 sA[128][32], sB[128][32];
    const int b = blockIdx.x;
    const int sb = (b & 7) * 27 + (b >> 3);
    const int bx = sb % 6, by = sb / 6;
    const int m0 = by * 128, n0 = bx * 128;
    const int tid = threadIdx.x, lane = tid & 63, wv = tid >> 6;
    const int wm = (wv >> 1) * 64, wn = (wv & 1) * 64;
    const int fr = lane & 15, fkb = (lane >> 4) * 8;

    const int srow = tid >> 2, scol = (tid & 3) * 8;
    const _Float16* gA = A + (size_t)(m0 + srow) * LD + scol;
    const _Float16* gB = B + (size_t)(n0 + srow) * LD + scol;

    f32x4 acc[4][4];
#pragma unroll
    for (int m = 0; m < 4; ++m)
#pragma unroll
        for (int n2 = 0; n2 < 4; ++n2) acc[m][n2] = (f32x4){0.f, 0.f, 0.f, 0.f};

    for (int kt = 0; kt < 24; ++kt) {
        const int k0 = kt * 32;
        gload16(&sA[srow][scol],      gA + k0);
        gload16(&sA[64 + srow][scol], gA + 64 * LD + k0);
        gload16(&sB[srow][scol],      gB + k0);
        gload16(&sB[64 + srow][scol], gB + 64 * LD + k0);
        __syncthreads();

        h8v fa[4], fb[4];
#pragma unroll
        for (int m = 0; m < 4; ++m) fa[m] = *(const h8v*)&sA[wm + m * 16 + fr][fkb];
#pragma unroll
        for (int n2 = 0; n2 < 4; ++n2) fb[n2] = *(const h8v*)&sB[wn + n2 * 16 + fr][fkb];
#pragma unroll
        for (int m = 0; m < 4; ++m)
#pragma unroll
            for (int n2 = 0; n2 < 4; ++n2) acc[m][n2] = MFMAH(fa[m], fb[n2], acc[m][n2]);
        __syncthreads();
    }

    const int rg = (lane >> 4) * 4;
#pragma unroll
    for (int m = 0; m < 4; ++m)
#pragma unroll
        for (int n2 = 0; n2 < 4; ++n2)
#pragma unroll
            for (int r = 0; r < 4; ++r)
                C[(size_t)(m0 + wm + m * 16 + rg + r) * LDC + (n0 + wn + n2 * 16 + fr)] =
                    acc[m][n2][r];
}

// ---------------------------------------------------------------------------
extern "C" void kernel_launch(void* const* d_in, const int* in_sizes, int n_in,
                              void* d_out, int out_size, void* d_ws, size_t ws_size,
                              hipStream_t stream) {
    const float* x     = (const float*)d_in[0];
    const float* w_qkv = (const float*)d_in[1];
    const float* w_out = (const float*)d_in[2];
    const int*   ksp   = (const int*)d_in[3];
    float* out = (float*)d_out;

    char* ws = (char*)d_ws;
    // layout (bytes):
    _Float16* qkv  = (_Float16*)(ws);                  // [0, 21,233,664)
    _Float16* vt   = (_Float16*)(ws + 21237760);       // +7,077,888 -> 28,315,648
    _Float16* o    = (_Float16*)(ws + 28315648);       // +7,077,888 -> 35,393,536
    _Float16* xh   = (_Float16*)(ws + 35393536);       // +7,077,888 (dead after gemm_qkv)
    _Float16* wqh  = (_Float16*)(ws + 42471424);       // +3,538,944 (dead after gemm_qkv)
    char*     part = (char*)(ws + 35393536);           // aliases xh/wqh: +15,040,512 -> 50,434,048
    _Float16* woh  = (_Float16*)(ws + 50434048);       // +1,179,648 -> 51,613,696 total

    conv_fp16<<<dim3(1728), 256, 0, stream>>>(x, xh, 442368);
    conv_fp16<<<dim3(864),  256, 0, stream>>>(w_qkv, wqh, 221184);
    conv_fp16<<<dim3(288),  256, 0, stream>>>(w_out, woh, 73728);

    gemm_qkv_f16<<<dim3(648), 256, 0, stream>>>(xh, wqh, qkv);
    vtrans<<<dim3(36, 12, 2), 256, 0, stream>>>((const unsigned short*)qkv,
                                                (unsigned short*)vt);
    attn_split<<<dim3(6912), 64, 0, stream>>>(qkv, vt, part, ksp);
    attn_combine<<<dim3(3456), 64, 0, stream>>>(part, o);
    gemm_out_f16<<<dim3(216), 256, 0, stream>>>(o, woh, out);
}